// Round 9
// baseline (2383.538 us; speedup 1.0000x reference)
//
#include <hip/hip_runtime.h>
#include <hip/hip_bf16.h>

#define B_ 1024
#define T_ 128
#define E_ 128
#define U_ 512
#define V_ 32000
#define NC 16   // col chunks (blocks per group)
#define NG 16   // row groups
#define MB 64   // rows per group
#define NB 32   // cols per chunk
#define HS ((size_t)B_ * U_)

#define CTR_OFF 0
#define XMASK_OFF (512u << 10)
#define FH0_OFF (520u << 10)
#define FH1_OFF (528u << 10)
#define H0H_OFF (1u << 20)
#define H0L_OFF (3u << 20)
#define H1H_OFF (5u << 20)
#define H1L_OFF (7u << 20)
#define EMBW_OFF (9u << 20)
#define ZERO_BYTES (9u << 20)

typedef unsigned int uint32;
typedef __bf16 bf16x8 __attribute__((ext_vector_type(8)));
typedef float f32x4 __attribute__((ext_vector_type(4)));
typedef unsigned short us8 __attribute__((ext_vector_type(8)));

#define MFMA __builtin_amdgcn_mfma_f32_16x16x32_bf16

__device__ __forceinline__ unsigned short f2b(float f) {
  uint32 u = __builtin_bit_cast(uint32, f);
  u += 0x7fffu + ((u >> 16) & 1u);   // RNE
  return (unsigned short)(u >> 16);
}
__device__ __forceinline__ float b2f(unsigned short h) {
  return __builtin_bit_cast(float, (uint32)h << 16);
}

// Swizzled LDS fragment read: row-major [row][K] bf16, byte ^= (row&7)<<4
__device__ __forceinline__ bf16x8 lds_frag(const unsigned short* s, int row, int k, int K) {
  uint32 off = (uint32)((row * K + k) * 2) ^ (uint32)((row & 7) << 4);
  us8 v = *(const us8*)((const char*)s + off);
  return __builtin_bit_cast(bf16x8, v);
}
__device__ __forceinline__ bf16x8 g_frag(const unsigned short* p) {
  us8 v = *(const us8*)p;
  return __builtin_bit_cast(bf16x8, v);
}
// Device-coherent h store (sc1 write-through; cross-XCD fallback path).
__device__ __forceinline__ void st_coh(unsigned short* p, unsigned short v) {
  __hip_atomic_store(p, v, __ATOMIC_RELAXED, __HIP_MEMORY_SCOPE_AGENT);
}
template <bool FAST>
__device__ __forceinline__ void st_h(unsigned short* p, unsigned short v) {
  if (FAST) *p = v; else st_coh(p, v);
}

// Per-wave release: drain own stores to L2/IF, then lane 0 publishes the flag.
template <bool FAST>
__device__ __forceinline__ void wave_signal(uint32* f, uint32 val, int lane) {
  asm volatile("s_waitcnt vmcnt(0)" ::: "memory");
  if (lane == 0) {
    if (FAST) *(volatile uint32*)f = val;  // plain: write-through to local L2
    else __hip_atomic_store(f, val, __ATOMIC_RELAXED, __HIP_MEMORY_SCOPE_AGENT);
  }
}

// Per-wave wait: lanes 0-15 poll flagH0 (>= t), lanes 16-31 poll flagH1
// (>= t-1). FAST: plain volatile loads + L1 buffer_inv per retry (L2-served,
// zero IF atomics). SLOW: agent-relaxed atomic loads + acquire fence.
template <bool FAST>
__device__ __forceinline__ void wave_wait(const uint32* f0, const uint32* f1,
                                          int t, int lane) {
  if (t == 0) return;
  const uint32 tgt = (lane < 16) ? (uint32)t : ((lane < 32) ? (uint32)(t - 1) : 0u);
  const uint32* p = (lane < 16) ? (f0 + lane) : (f1 + (lane & 15));
  while (true) {
    uint32 v;
    if (FAST) v = *(const volatile uint32*)p;
    else v = __hip_atomic_load(p, __ATOMIC_RELAXED, __HIP_MEMORY_SCOPE_AGENT);
    if (__all(v >= tgt)) break;
    if (FAST) asm volatile("buffer_inv" ::: "memory");
    __builtin_amdgcn_s_sleep(2);
  }
  if (FAST) asm volatile("buffer_inv\n\ts_waitcnt vmcnt(0)" ::: "memory");
  else __builtin_amdgcn_fence(__ATOMIC_ACQUIRE, "agent");
}

// Block-level group barrier (used ONCE for the XCD co-residency check).
__device__ __forceinline__ void bar_agent(uint32* ctr, int phase, int g, int tid) {
  asm volatile("s_waitcnt vmcnt(0)" ::: "memory");
  __syncthreads();
  if (tid == 0) {
    uint32* a = &ctr[(uint32)((phase << 4) | g) << 4];
    __hip_atomic_fetch_add(a, 1u, __ATOMIC_RELAXED, __HIP_MEMORY_SCOPE_AGENT);
    while (__hip_atomic_load(a, __ATOMIC_RELAXED, __HIP_MEMORY_SCOPE_AGENT) < NC)
      __builtin_amdgcn_s_sleep(1);
    __builtin_amdgcn_fence(__ATOMIC_ACQUIRE, "agent");
  }
  __syncthreads();
}

__global__ void rnn_init(unsigned char* ws) {
  const uint4 z = {0u, 0u, 0u, 0u};
  uint4* p = (uint4*)ws;
  size_t n = ZERO_BYTES / 16;
  for (size_t j = (size_t)blockIdx.x * blockDim.x + threadIdx.x; j < n;
       j += (size_t)gridDim.x * blockDim.x)
    p[j] = z;
}

// embW[v][u] = sum_e emb[v][e] * Wx0[e][u], stored bf16. grid (V/64, U/64), 256 thr.
__global__ __launch_bounds__(256) void embw_gemm(const float* __restrict__ emb,
                                                 const float* __restrict__ Wx0,
                                                 unsigned short* __restrict__ embW) {
  const int tid = threadIdx.x;
  const int lane = tid & 63;
  const int wv = tid >> 6;
  const int arow = lane & 15;
  const int kgrp = (lane >> 4) * 8;
  const int vrow = blockIdx.x * 64 + wv * 16;

  bf16x8 a[4];
  for (int kt = 0; kt < 4; ++kt) {
    const float* p = emb + (size_t)(vrow + arow) * E_ + kt * 32 + kgrp;
    float4 f0 = ((const float4*)p)[0];
    float4 f1 = ((const float4*)p)[1];
    us8 u;
    u[0] = f2b(f0.x); u[1] = f2b(f0.y); u[2] = f2b(f0.z); u[3] = f2b(f0.w);
    u[4] = f2b(f1.x); u[5] = f2b(f1.y); u[6] = f2b(f1.z); u[7] = f2b(f1.w);
    a[kt] = __builtin_bit_cast(bf16x8, u);
  }
  const int c0 = blockIdx.y * 64;
  for (int nt = 0; nt < 4; ++nt) {
    const int col = c0 + nt * 16 + (lane & 15);
    f32x4 acc = {0.f, 0.f, 0.f, 0.f};
    for (int kt = 0; kt < 4; ++kt) {
      us8 ub;
      for (int j = 0; j < 8; ++j)
        ub[j] = f2b(Wx0[(size_t)(kt * 32 + kgrp + j) * U_ + col]);
      acc = MFMA(a[kt], __builtin_bit_cast(bf16x8, ub), acc, 0, 0, 0);
    }
    const int crow = vrow + (lane >> 4) * 4;
    for (int i = 0; i < 4; ++i)
      embW[(size_t)(crow + i) * U_ + col] = f2b(acc[i]);
  }
}

template <bool FAST>
__device__ __forceinline__ void rnn_loop(
    const int* __restrict__ tokens, const unsigned short* __restrict__ embW,
    unsigned short* h0h, unsigned short* h0l, unsigned short* h1h,
    unsigned short* h1l, const uint32* f0w, const uint32* f1w, uint32* myF0,
    uint32* myF1, const unsigned short* sWh0h, const unsigned short* sWh0l,
    const unsigned short* sWx1h, const unsigned short* sWh1h,
    const unsigned short* sWh1l, int r0, int c0, int lane, int rowB, int kgrp,
    int rowA, float b0v0, float b0v1, float b1v0, float b1v1) {
  const int l15 = lane & 15;
  const float b0a[2] = {b0v0, b0v1};
  const float b1a[2] = {b1v0, b1v1};

  unsigned short embP[2][4];
#pragma unroll
  for (int nt = 0; nt < 2; ++nt)
    for (int i = 0; i < 4; ++i) {
      int tk = tokens[(size_t)(r0 + rowB + i) * T_ + 0];
      embP[nt][i] = embW[(size_t)tk * U_ + c0 + nt * 16 + l15];
    }

  for (int t = 0; t <= T_; ++t) {
    wave_wait<FAST>(f0w, f1w, t, lane);

    // ---- batch-issue ALL loads for this window (MLP ~72) ----
    const size_t rb0 = (size_t)((t & 1) ^ 1) * HS;  // h0'(t-1)
    bf16x8 h0h_r[16], h0l_r[16];
    {
      const unsigned short* aph = h0h + rb0 + (size_t)rowA * U_ + kgrp;
      const unsigned short* apl = h0l + rb0 + (size_t)rowA * U_ + kgrp;
#pragma unroll
      for (int kt = 0; kt < 16; ++kt) {
        h0h_r[kt] = g_frag(aph + kt * 32);
        h0l_r[kt] = g_frag(apl + kt * 32);
      }
    }
    bf16x8 a1h_r[16], a1l_r[16];
    if (t >= 1) {
      const size_t rb1 = (size_t)(t & 1) * HS;  // h1'(t-2)
      const unsigned short* a1h = h1h + rb1 + (size_t)rowA * U_ + kgrp;
      const unsigned short* a1l = h1l + rb1 + (size_t)rowA * U_ + kgrp;
#pragma unroll
      for (int kt = 0; kt < 16; ++kt) {
        a1h_r[kt] = g_frag(a1h + kt * 32);
        a1l_r[kt] = g_frag(a1l + kt * 32);
      }
    }
    unsigned short embN[2][4];
    if (t + 1 < T_) {
#pragma unroll
      for (int nt = 0; nt < 2; ++nt)
        for (int i = 0; i < 4; ++i) {
          int tk = tokens[(size_t)(r0 + rowB + i) * T_ + (t + 1)];
          embN[nt][i] = embW[(size_t)tk * U_ + c0 + nt * 16 + l15];
        }
    }

    // ---- layer 0 FIRST (critical recurrence): h0'(t), release flagH0 ----
    if (t < T_) {
      const size_t wbuf = (size_t)(t & 1) * HS;
#pragma unroll
      for (int nt = 0; nt < 2; ++nt) {
        const int colL = nt * 16 + l15;
        f32x4 aC, aD = {0.f, 0.f, 0.f, 0.f};
        for (int i = 0; i < 4; ++i) aC[i] = b0a[nt] + b2f(embP[nt][i]);
#pragma unroll
        for (int kt = 0; kt < 16; ++kt) {
          bf16x8 bh = lds_frag(sWh0h, colL, kt * 32 + kgrp, U_);
          bf16x8 bl = lds_frag(sWh0l, colL, kt * 32 + kgrp, U_);
          aC = MFMA(h0h_r[kt], bh, aC, 0, 0, 0);
          aD = MFMA(h0l_r[kt], bh, aD, 0, 0, 0);
          aD = MFMA(h0h_r[kt], bl, aD, 0, 0, 0);
        }
        size_t ob = wbuf + (size_t)(r0 + rowB) * U_ + (c0 + colL);
        for (int i = 0; i < 4; ++i) {
          float v = tanhf(aC[i] + aD[i]);
          unsigned short hi = f2b(v);
          st_h<FAST>(&h0h[ob + (size_t)i * U_], hi);
          st_h<FAST>(&h0l[ob + (size_t)i * U_], f2b(v - b2f(hi)));
        }
      }
      wave_signal<FAST>(myF0, (uint32)(t + 1), lane);
    }

    // ---- layer 1 (lagged): h1'(t-1), release flagH1 ----
    if (t >= 1) {
      const size_t wb1 = (size_t)((t - 1) & 1) * HS;
#pragma unroll
      for (int nt = 0; nt < 2; ++nt) {
        const int colL = nt * 16 + l15;
        f32x4 aA = {0.f, 0.f, 0.f, 0.f};
        f32x4 aB = {b1a[nt], b1a[nt], b1a[nt], b1a[nt]};
#pragma unroll
        for (int kt = 0; kt < 16; ++kt) {
          bf16x8 bxh = lds_frag(sWx1h, colL, kt * 32 + kgrp, U_);
          aA = MFMA(h0h_r[kt], bxh, aA, 0, 0, 0);
          aA = MFMA(h0l_r[kt], bxh, aA, 0, 0, 0);
          bf16x8 bh = lds_frag(sWh1h, colL, kt * 32 + kgrp, U_);
          aB = MFMA(a1h_r[kt], bh, aB, 0, 0, 0);
          aB = MFMA(a1l_r[kt], bh, aB, 0, 0, 0);
          if (kt < 15) {
            bf16x8 bl = lds_frag(sWh1l, colL, kt * 32 + kgrp, 480);
            aB = MFMA(a1h_r[kt], bl, aB, 0, 0, 0);
          }
        }
        size_t ob = wb1 + (size_t)(r0 + rowB) * U_ + (c0 + colL);
        for (int i = 0; i < 4; ++i) {
          float v = tanhf(aA[i] + aB[i]);
          unsigned short hi = f2b(v);
          st_h<FAST>(&h1h[ob + (size_t)i * U_], hi);
          st_h<FAST>(&h1l[ob + (size_t)i * U_], f2b(v - b2f(hi)));
        }
      }
      wave_signal<FAST>(myF1, (uint32)t, lane);
    }

    if (t + 1 < T_) {
#pragma unroll
      for (int nt = 0; nt < 2; ++nt)
        for (int i = 0; i < 4; ++i) embP[nt][i] = embN[nt][i];
    }
  }
}

__global__ __launch_bounds__(256, 1) void rnn_main(
    const int* __restrict__ tokens, const float* __restrict__ b0,
    const float* __restrict__ Wh0, const float* __restrict__ Wx1,
    const float* __restrict__ Wh1, const float* __restrict__ b1,
    unsigned char* ws) {
  __shared__ unsigned short sWh0h[NB * U_];   // 32 KB
  __shared__ unsigned short sWh0l[NB * U_];   // 32 KB
  __shared__ unsigned short sWx1h[NB * U_];   // 32 KB
  __shared__ unsigned short sWh1h[NB * U_];   // 32 KB
  __shared__ unsigned short sWh1l[NB * 480];  // 30 KB
  __shared__ uint32 sFast;

  const int tid = threadIdx.x;
  const int bid = blockIdx.x;
  const int g = bid & (NG - 1);
  const int c = bid >> 4;
  const int r0 = g * MB;
  const int c0 = c * NB;

  uint32* ctr = (uint32*)(ws + CTR_OFF);
  uint32* fH0 = (uint32*)(ws + FH0_OFF);
  uint32* fH1 = (uint32*)(ws + FH1_OFF);
  unsigned short* h0h = (unsigned short*)(ws + H0H_OFF);
  unsigned short* h0l = (unsigned short*)(ws + H0L_OFF);
  unsigned short* h1h = (unsigned short*)(ws + H1H_OFF);
  unsigned short* h1l = (unsigned short*)(ws + H1L_OFF);
  const unsigned short* embW = (const unsigned short*)(ws + EMBW_OFF);

  // ---- stage weight slices: f32 global -> bf16 hi(+lo) swizzled LDS ----
  for (int idx = tid; idx < NB * U_; idx += 256) {
    int cl = idx & 31, k = idx >> 5;
    float v = Wh0[(size_t)k * U_ + c0 + cl];
    unsigned short hi = f2b(v);
    uint32 off = (uint32)((cl * U_ + k) * 2) ^ (uint32)((cl & 7) << 4);
    *(unsigned short*)((char*)sWh0h + off) = hi;
    *(unsigned short*)((char*)sWh0l + off) = f2b(v - b2f(hi));
  }
  for (int idx = tid; idx < NB * U_; idx += 256) {
    int cl = idx & 31, k = idx >> 5;
    float v = Wx1[(size_t)k * U_ + c0 + cl];
    uint32 off = (uint32)((cl * U_ + k) * 2) ^ (uint32)((cl & 7) << 4);
    *(unsigned short*)((char*)sWx1h + off) = f2b(v);
  }
  for (int idx = tid; idx < NB * U_; idx += 256) {
    int cl = idx & 31, k = idx >> 5;
    float v = Wh1[(size_t)k * U_ + c0 + cl];
    unsigned short hi = f2b(v);
    uint32 off = (uint32)((cl * U_ + k) * 2) ^ (uint32)((cl & 7) << 4);
    *(unsigned short*)((char*)sWh1h + off) = hi;
    if (k < 480) {
      uint32 offl = (uint32)((cl * 480 + k) * 2) ^ (uint32)((cl & 7) << 4);
      *(unsigned short*)((char*)sWh1l + offl) = f2b(v - b2f(hi));
    }
  }

  // ---- runtime XCD co-residency check (G16: never ASSUME the mapping) ----
  // Each block's fetch_or is drained (vmcnt) before its counter add inside
  // bar_agent, so after the barrier every block reads the SAME final mask ->
  // the FAST/SLOW decision is group-uniform by construction.
  {
    uint32 xcd;
    asm volatile("s_getreg_b32 %0, hwreg(HW_REG_XCC_ID)" : "=s"(xcd));
    uint32* xm = (uint32*)(ws + XMASK_OFF) + (uint32)g * 16;
    if (tid == 0)
      __hip_atomic_fetch_or(xm, 1u << (xcd & 31u), __ATOMIC_RELAXED,
                            __HIP_MEMORY_SCOPE_AGENT);
    bar_agent(ctr, T_, g, tid);
    if (tid == 0) {
      uint32 m = __hip_atomic_load(xm, __ATOMIC_RELAXED, __HIP_MEMORY_SCOPE_AGENT);
      sFast = (__popc(m) == 1) ? 1u : 0u;
    }
  }

  const int lane = tid & 63;
  const int mt = tid >> 6;  // 4 waves = 4 M-tiles; each wave owns 16 rows x 32 cols
  const int l15 = lane & 15;
  const int rowB = mt * 16 + ((lane >> 4) << 2);
  const int kgrp = (lane >> 4) * 8;
  const int rowA = r0 + mt * 16 + l15;
  const float b0v0 = b0[c0 + l15], b0v1 = b0[c0 + 16 + l15];
  const float b1v0 = b1[c0 + l15], b1v1 = b1[c0 + 16 + l15];

  const uint32* f0w = fH0 + (((uint32)g * 4 + mt) << 4);
  const uint32* f1w = fH1 + (((uint32)g * 4 + mt) << 4);
  uint32* myF0 = (uint32*)f0w + c;
  uint32* myF1 = (uint32*)f1w + c;

  __syncthreads();  // weights staged + sFast visible; no syncs after this
  const bool fast = (sFast != 0);

  if (fast)
    rnn_loop<true>(tokens, embW, h0h, h0l, h1h, h1l, f0w, f1w, myF0, myF1,
                   sWh0h, sWh0l, sWx1h, sWh1h, sWh1l, r0, c0, lane, rowB, kgrp,
                   rowA, b0v0, b0v1, b1v0, b1v1);
  else
    rnn_loop<false>(tokens, embW, h0h, h0l, h1h, h1l, f0w, f1w, myF0, myF1,
                    sWh0h, sWh0l, sWx1h, sWh1h, sWh1l, r0, c0, lane, rowB, kgrp,
                    rowA, b0v0, b0v1, b1v0, b1v1);
}

__global__ void rnn_final(const unsigned short* __restrict__ h1h,
                          const unsigned short* __restrict__ h1l,
                          const float* __restrict__ Wo,
                          const float* __restrict__ bo, float* __restrict__ out) {
  int lane = threadIdx.x & 63;
  int b = blockIdx.x * 4 + (threadIdx.x >> 6);
  us8 hh = *(const us8*)(h1h + (size_t)b * U_ + lane * 8);
  us8 hl = *(const us8*)(h1l + (size_t)b * U_ + lane * 8);
  const float4* wp = (const float4*)(Wo + lane * 8);
  float4 w0 = wp[0], w1 = wp[1];
  float s = (b2f(hh[0]) + b2f(hl[0])) * w0.x + (b2f(hh[1]) + b2f(hl[1])) * w0.y +
            (b2f(hh[2]) + b2f(hl[2])) * w0.z + (b2f(hh[3]) + b2f(hl[3])) * w0.w +
            (b2f(hh[4]) + b2f(hl[4])) * w1.x + (b2f(hh[5]) + b2f(hl[5])) * w1.y +
            (b2f(hh[6]) + b2f(hl[6])) * w1.z + (b2f(hh[7]) + b2f(hl[7])) * w1.w;
  for (int off = 32; off > 0; off >>= 1) s += __shfl_down(s, off, 64);
  if (lane == 0) out[b] = 1.0f / (1.0f + expf(-(s + bo[0])));
}

extern "C" void kernel_launch(void* const* d_in, const int* in_sizes, int n_in,
                              void* d_out, int out_size, void* d_ws, size_t ws_size,
                              hipStream_t stream) {
  const int* tokens = (const int*)d_in[0];
  const float* emb = (const float*)d_in[1];
  const float* Wx0 = (const float*)d_in[2];
  const float* Wh0 = (const float*)d_in[3];
  const float* b0 = (const float*)d_in[4];
  const float* Wx1 = (const float*)d_in[5];
  const float* Wh1 = (const float*)d_in[6];
  const float* b1 = (const float*)d_in[7];
  const float* Wo = (const float*)d_in[8];
  const float* bo = (const float*)d_in[9];
  unsigned char* ws = (unsigned char*)d_ws;
  float* out = (float*)d_out;

  hipLaunchKernelGGL(rnn_init, dim3(1024), dim3(256), 0, stream, ws);
  hipLaunchKernelGGL(embw_gemm, dim3(V_ / 64, U_ / 64), dim3(256), 0, stream,
                     emb, Wx0, (unsigned short*)(ws + EMBW_OFF));
  hipLaunchKernelGGL(rnn_main, dim3(NC * NG), dim3(256), 0, stream, tokens,
                     b0, Wh0, Wx1, Wh1, b1, ws);
  // final h1'(127) lives in buffer (127)&1 == 1
  hipLaunchKernelGGL(rnn_final, dim3(256), dim3(256), 0, stream,
                     (const unsigned short*)(ws + H1H_OFF) + (size_t)1 * B_ * U_,
                     (const unsigned short*)(ws + H1L_OFF) + (size_t)1 * B_ * U_,
                     Wo, bo, out);
}